// Round 5
// baseline (146.228 us; speedup 1.0000x reference)
//
#include <hip/hip_runtime.h>

// TcEmbedding: x (B=4, S=4096, D=64) f32.
// norms[b,t] = sum_d |x[b,t,d]|
// tc[b,t]   = t - j, j = nearest index < t with norms[j] < 0.7*(norms[t]+1e-8), else 0.
//
// R5: ONE plain kernel (no cooperative launch — R4 showed it costs ~45us in
// a captured graph). 256 blocks x 1024 thr; block = one 64-t chunk.
// Phase 1: own-chunk norms in one wave-round (float4, f64 acc) -> publish
// norms + chunk-min (release/agent atomic). Phase 2: spin-acquire earlier
// chunks' minima (ws 0xAA poison = negative double -> `>0` is the ready
// flag), then the R2/R3 two-level ballot search. Bounded spin + recompute
// fallback as deadlock insurance (256 blocks are trivially co-resident).
// Harness floor: ~41us ws re-poison fill + ~4us restore/overhead.

#define SS 4096
typedef unsigned long long u64;

// One-wave recompute of a chunk's 64 L1 norms (fallback path only).
// Leaves norm of row r in scratch[r]; returns chunk min (replicated).
__device__ __noinline__ double chunk_norms_from_x(
    const float4* __restrict__ x4, int globalChunk, int lane,
    volatile double* scratch)
{
    double mn = 1e300;
    int g = lane >> 4;           // row-group within round
    int e = lane & 15;           // float4 index within row
    for (int r = 0; r < 16; ++r) {
        int row = globalChunk * 64 + r * 4 + g;
        float4 p = x4[row * 16 + e];
        double a = (double)fabsf(p.x) + (double)fabsf(p.y)
                 + (double)fabsf(p.z) + (double)fabsf(p.w);
        #pragma unroll
        for (int off = 8; off > 0; off >>= 1)
            a += __shfl_xor(a, off, 64);
        if (e == 0) scratch[r * 4 + g] = a;
        mn = (a < mn) ? a : mn;
    }
    #pragma unroll
    for (int off = 16; off < 64; off <<= 1) {
        double o = __shfl_xor(mn, off, 64);
        mn = (o < mn) ? o : mn;
    }
    return mn;
}

__global__ void __launch_bounds__(1024)
tc_fused_kernel(const float4* __restrict__ x4, double* __restrict__ nrm,
                double* __restrict__ cmn, float* __restrict__ out)
{
    __shared__ double sn[64];          // own chunk's norms
    __shared__ double sfall[16][64];   // per-wave fallback scratch (8 KB)

    int ci   = blockIdx.x;             // b*64 + c
    int b    = ci >> 6;
    int c    = ci & 63;
    int wave = threadIdx.x >> 6;
    int lane = threadIdx.x & 63;
    int g    = lane >> 4;
    int e    = lane & 15;

    // ---- Phase 1: own chunk's 64 norms in ONE round (16 waves x 4 rows) ---
    {
        int rlocal = wave * 4 + g;
        int row    = ci * 64 + rlocal;
        float4 p = x4[row * 16 + e];
        double a = (double)fabsf(p.x) + (double)fabsf(p.y)
                 + (double)fabsf(p.z) + (double)fabsf(p.w);
        #pragma unroll
        for (int off = 8; off > 0; off >>= 1)      // 16-lane group reduce
            a += __shfl_xor(a, off, 64);
        if (e == 0) { nrm[row] = a; sn[rlocal] = a; }
    }
    __syncthreads();
    if (threadIdx.x < 64) {                        // wave 0: publish chunk min
        double m = sn[lane];
        #pragma unroll
        for (int off = 32; off > 0; off >>= 1) {
            double o = __shfl_xor(m, off, 64);
            m = (o < m) ? o : m;
        }
        if (lane == 0) {
            __threadfence();                       // norms visible before flag
            __hip_atomic_store((u64*)&cmn[ci], __builtin_bit_cast(u64, m),
                               __ATOMIC_RELEASE, __HIP_MEMORY_SCOPE_AGENT);
        }
    }

    // ---- Phase 2: spin-acquire earlier chunks' minima -----------------
    const u64* cp = (const u64*)(cmn + (b << 6) + lane);
    double cm = __builtin_bit_cast(double,
        __hip_atomic_load(cp, __ATOMIC_ACQUIRE, __HIP_MEMORY_SCOPE_AGENT));
    int spins = 0;
    bool timeout = false;
    while (__ballot((lane < c) && !(cm > 0.0))) {  // poison 0xAA.. is negative
        if (++spins > (1 << 20)) { timeout = true; break; }
        __builtin_amdgcn_s_sleep(8);
        cm = __builtin_bit_cast(double,
            __hip_atomic_load(cp, __ATOMIC_ACQUIRE, __HIP_MEMORY_SCOPE_AGENT));
    }
    u64 ready = ~0ull;                 // bit j: cmn[b*64+j] published
    if (timeout) {                      // insurance: recompute missing chunks
        ready = __ballot(cm > 0.0);
        for (int j = 0; j < c; ++j) {
            if (!((ready >> j) & 1)) {
                double m = chunk_norms_from_x(x4, (b << 6) + j, lane, sfall[wave]);
                if (lane == j) cm = m;
            }
        }
    }

    // ---- two-level ballot search; wave handles t = c*64 + wave*4 + k ----
    double v = sn[lane];
    int cached_cc = -1;
    double v2 = 0.0;
    float res[4];
    #pragma unroll
    for (int k = 0; k < 4; ++k) {
        int pos = wave * 4 + k;
        double thr = 0.7 * (sn[pos] + 1e-8);
        int r = 0;
        // (a) partial current chunk: j in [c*64, t)
        u64 m = __ballot(lane < pos && v < thr);
        if (m) {
            r = pos - (63 - __clzll(m));
        } else {
            // (b) nearest earlier chunk whose min qualifies
            u64 mc = __ballot(lane < c && cm < thr);
            if (mc) {
                int cc = 63 - __clzll(mc);         // wave-uniform
                if (cc != cached_cc) {
                    if ((ready >> cc) & 1) {
                        v2 = nrm[(b << 12) + (cc << 6) + lane];
                    } else {                        // fallback-only path
                        chunk_norms_from_x(x4, (b << 6) + cc, lane, sfall[wave]);
                        v2 = sfall[wave][lane];
                    }
                    cached_cc = cc;
                }
                // (c) nearest element within that chunk (non-empty by cmin)
                u64 m2 = __ballot(v2 < thr);
                r = ((c - cc) << 6) + pos - (63 - __clzll(m2));
            }
        }
        res[k] = (float)r;
    }
    if (lane == 0)
        ((float4*)out)[ci * 16 + wave] =
            make_float4(res[0], res[1], res[2], res[3]);
}

extern "C" void kernel_launch(void* const* d_in, const int* in_sizes, int n_in,
                              void* d_out, int out_size, void* d_ws, size_t ws_size,
                              hipStream_t stream) {
    const float4* x4 = (const float4*)d_in[0];
    float* out = (float*)d_out;
    int nrows  = in_sizes[0] / 64;      // B*S   = 16384
    int nchunk = nrows / 64;            // 256

    // f64 norms/compares: a flip near the 0.7 threshold changes tc by O(S)
    // >> absmax tolerance; f64 margins ~1e-13. (R1-R4: absmax 0.)
    double* nrm = (double*)d_ws;        // 16384 doubles
    double* cmn = nrm + nrows;          // 256 doubles (0xAA poison = negative)

    tc_fused_kernel<<<nchunk, 1024, 0, stream>>>(x4, nrm, cmn, out);
}

// Round 6
// 86.242 us; speedup vs baseline: 1.6956x; 1.6956x over previous
//
#include <hip/hip_runtime.h>

// TcEmbedding: x (B=4, S=4096, D=64) f32.
// norms[b,t] = sum_d |x[b,t,d]|
// tc[b,t]   = t - j, j = nearest index < t with norms[j] < 0.7*(norms[t]+1e-8), else 0.
//
// R6: ONE plain kernel, ZERO cross-block communication.
//  - R4 (cooperative grid.sync): +45us — coop launch serializes in a graph.
//  - R5 (spin on agent-scope atomics): 98us — every acquire is a cache-
//    maintenance op on multi-XCD hw; 4096 spinning waves thrash the TCC.
//  - R6: each block recomputes the full norm prefix it needs from x.
//    Total redundant reads = 133MB L2-warm (~4us aggregate); worst block
//    streams 1MB / 64 wave-rounds (~2us). Cheaper than any sync.
// Block = one 64-t chunk (256 blocks x 1024 thr). Wave w computes norms of
// chunks w, w+16, w+32, ... <= c into LDS (f64, deterministic order), plus
// per-chunk minima; __syncthreads(); two-level ballot search, all LDS.
// f64 norms/compares: a flip near the 0.7 threshold changes tc by O(S) >>
// absmax tolerance; f64 margin ~1e-13 (R1-R5: absmax 0).

#define SS 4096
typedef unsigned long long u64;

__global__ void __launch_bounds__(1024)
tc_onepass_kernel(const float4* __restrict__ x4, float* __restrict__ out)
{
    __shared__ double sn[SS];      // prefix norms for this row (<=32 KB used)
    __shared__ double cmin[64];    // per-chunk minima

    int ci   = blockIdx.x;         // b*64 + c
    int b    = ci >> 6;
    int c    = ci & 63;
    int wave = threadIdx.x >> 6;
    int lane = threadIdx.x & 63;
    int g    = lane >> 4;          // row-within-round (0..3)
    int e    = lane & 15;          // float4 index within row (0..15)

    const float4* xrow = x4 + (size_t)b * (SS * 16);

    // ---- Phase 1: norms of chunks 0..c; wave w -> chunks w, w+16, ... ----
    for (int ch = wave; ch <= c; ch += 16) {
        double mn = 1e300;
        #pragma unroll
        for (int rr = 0; rr < 16; ++rr) {          // 4 rows per round, 16 rounds
            int r = (ch << 6) + (rr << 2) + g;     // row index within batch row
            float4 p = xrow[r * 16 + e];           // 64 lanes = 4 rows, 1KB coalesced
            double a = (double)fabsf(p.x) + (double)fabsf(p.y)
                     + (double)fabsf(p.z) + (double)fabsf(p.w);
            #pragma unroll
            for (int off = 8; off > 0; off >>= 1)  // reduce within 16-lane group
                a += __shfl_xor(a, off, 64);
            if (e == 0) sn[r] = a;                 // f64 store, 2-way bank = free
            mn = (a < mn) ? a : mn;
        }
        #pragma unroll
        for (int off = 16; off < 64; off <<= 1) {  // min across the 4 groups
            double o = __shfl_xor(mn, off, 64);
            mn = (o < mn) ? o : mn;
        }
        if (lane == 0) cmin[ch] = mn;
    }
    __syncthreads();

    // ---- Phase 2: two-level ballot search; wave w -> t = c*64 + w*4 + k ----
    double v  = sn[(c << 6) + lane];               // own chunk's norms
    double cm = cmin[lane];                        // garbage for lane>c: gated below
    float res[4];
    #pragma unroll
    for (int k = 0; k < 4; ++k) {
        int pos = (wave << 2) + k;                 // t-in-chunk
        double thr = 0.7 * (sn[(c << 6) + pos] + 1e-8);
        int r = 0;
        // (a) partial current chunk: j in [c*64, t)
        u64 m = __ballot(lane < pos && v < thr);
        if (m) {                                    // wave-uniform branch
            r = pos - (63 - __clzll(m));
        } else {
            // (b) nearest earlier chunk whose min qualifies
            u64 mc = __ballot(lane < c && cm < thr);
            if (mc) {
                int cc = 63 - __clzll(mc);          // wave-uniform
                // (c) nearest element within that chunk (non-empty by cmin)
                double v2 = sn[(cc << 6) + lane];   // straight from LDS
                u64 m2 = __ballot(v2 < thr);
                r = ((c - cc) << 6) + pos - (63 - __clzll(m2));
            }
        }
        res[k] = (float)r;
    }
    if (lane == 0)
        ((float4*)out)[ci * 16 + wave] =
            make_float4(res[0], res[1], res[2], res[3]);
}

extern "C" void kernel_launch(void* const* d_in, const int* in_sizes, int n_in,
                              void* d_out, int out_size, void* d_ws, size_t ws_size,
                              hipStream_t stream) {
    const float4* x4 = (const float4*)d_in[0];
    float* out = (float*)d_out;
    int nrows  = in_sizes[0] / 64;      // B*S   = 16384
    int nchunk = nrows / 64;            // 256 blocks, one per 64-t chunk

    (void)d_ws; (void)ws_size;          // no workspace, no sync, no atomics
    tc_onepass_kernel<<<nchunk, 1024, 0, stream>>>(x4, out);
}

// Round 7
// 57.340 us; speedup vs baseline: 2.5502x; 1.5040x over previous
//
#include <hip/hip_runtime.h>

// TcEmbedding: x (B=4, S=4096, D=64) f32.
// norms[b,t] = sum_d |x[b,t,d]|
// tc[b,t]   = t - j, j = nearest index < t with norms[j] < 0.7*(norms[t]+1e-8), else 0.
//
// R7: back to the balanced two-kernel structure (R3 = 58.1us best), leaner.
// Failed-branch ledger: R4 coop grid.sync +45us (graph-serialized);
// R5 agent-scope spin 98us (acquire = cache maintenance on 8 XCDs);
// R6 prefix-recompute 43us (worst block pushes 64 chunk-reduces through one
// CU's LDS pipe). Norms must be computed ONCE per chunk; the kernel boundary
// is the cheapest correct barrier on this chip.
//  A: block = chunk (256 blocks x 1024thr): wave w -> rows 4w..4w+3 in ONE
//     float4 round, f64 4-stage shuffle reduce, block min via 16-entry LDS.
//  B: block = chunk: stage own-chunk norms + cmin row into LDS once, 16
//     waves x 4 t two-level ballot search; step-(c) chunk read from L2.
// f64 norms/compares throughout: a compare flip near the 0.7 threshold
// changes tc by O(S) >> absmax tolerance (R1-R6: absmax 0).

#define SS 4096
typedef unsigned long long u64;

// ---------------- Kernel A: norms + chunk minima, one round per wave -------
template <typename T>
__global__ void __launch_bounds__(1024)
tc_norms_kernel(const float4* __restrict__ x4, T* __restrict__ nrm,
                T* __restrict__ cmn)
{
    __shared__ T smin[16];
    int ci   = blockIdx.x;              // chunk id = b*64 + c
    int wave = threadIdx.x >> 6;
    int lane = threadIdx.x & 63;
    int g    = lane >> 4;               // row within wave's 4 (0..3)
    int e    = lane & 15;               // float4 index within row

    int row = (ci << 6) + (wave << 2) + g;
    float4 p = x4[row * 16 + e];        // 64 lanes = 4 rows, 1KB coalesced
    T a = (T)fabsf(p.x) + (T)fabsf(p.y) + (T)fabsf(p.z) + (T)fabsf(p.w);
    #pragma unroll
    for (int off = 8; off > 0; off >>= 1)   // reduce within 16-lane group
        a += __shfl_xor(a, off, 64);
    if (e == 0) nrm[row] = a;               // lane e==0 holds the row norm

    // wave min over its 4 rows (valid only at e==0 lanes; mask others)
    T m = (e == 0) ? a : (T)1e300;
    {
        T o = __shfl_xor(m, 16, 64); m = (o < m) ? o : m;
        o   = __shfl_xor(m, 32, 64); m = (o < m) ? o : m;
    }
    if (lane == 0) smin[wave] = m;
    __syncthreads();
    if (threadIdx.x < 16) {                 // wave 0: min across 16 waves
        T m2 = smin[threadIdx.x];
        #pragma unroll
        for (int off = 8; off > 0; off >>= 1) {
            T o = __shfl_xor(m2, off, 64);
            m2 = (o < m2) ? o : m2;
        }
        if (threadIdx.x == 0) cmn[ci] = m2;
    }
}

// ---------------- Kernel B: two-level ballot search, LDS-staged ------------
template <typename T>
__global__ void __launch_bounds__(1024)
tc_scan_kernel(const T* __restrict__ nrm, const T* __restrict__ cmn,
               float* __restrict__ out)
{
    __shared__ T sn[64];                // own chunk's norms
    __shared__ T scm[64];               // row's 64 chunk minima
    int ci   = blockIdx.x;              // b*64 + c
    int b    = ci >> 6;
    int c    = ci & 63;
    int wave = threadIdx.x >> 6;
    int lane = threadIdx.x & 63;

    if (wave == 0)      sn[lane]  = nrm[(ci << 6) + lane];
    else if (wave == 1) scm[lane] = cmn[(b << 6) + lane];
    __syncthreads();

    T v  = sn[lane];
    T cm = scm[lane];
    float res[4];
    #pragma unroll
    for (int k = 0; k < 4; ++k) {
        int pos = (wave << 2) + k;      // t = c*64 + pos
        T thr = (T)0.7 * (sn[pos] + (T)1e-8);
        int r = 0;
        // (a) partial current chunk: j in [c*64, t)
        u64 m = __ballot(lane < pos && v < thr);
        if (m) {                        // wave-uniform (m is scalar)
            r = pos - (63 - __clzll(m));
        } else {
            // (b) nearest earlier chunk whose min qualifies
            u64 mc = __ballot(lane < c && cm < thr);
            if (mc) {
                int cc = 63 - __clzll(mc);                 // wave-uniform
                // (c) nearest element in that chunk (non-empty by cmin), L2
                T v2 = nrm[(b << 12) + (cc << 6) + lane];
                u64 m2 = __ballot(v2 < thr);
                r = ((c - cc) << 6) + pos - (63 - __clzll(m2));
            }
        }
        res[k] = (float)r;
    }
    if (lane == 0)
        ((float4*)out)[ci * 16 + wave] =
            make_float4(res[0], res[1], res[2], res[3]);
}

extern "C" void kernel_launch(void* const* d_in, const int* in_sizes, int n_in,
                              void* d_out, int out_size, void* d_ws, size_t ws_size,
                              hipStream_t stream) {
    const float4* x4 = (const float4*)d_in[0];
    float* out = (float*)d_out;
    int nrows  = in_sizes[0] / 64;      // B*S   = 16384
    int nchunk = nrows / 64;            // 256

    if (ws_size >= (size_t)(nrows + nchunk) * sizeof(double)) {
        double* nrm = (double*)d_ws;
        double* cmn = nrm + nrows;
        tc_norms_kernel<double><<<nchunk, 1024, 0, stream>>>(x4, nrm, cmn);
        tc_scan_kernel<double><<<nchunk, 1024, 0, stream>>>(nrm, cmn, out);
    } else {
        float* nrm = (float*)d_ws;
        float* cmn = nrm + nrows;
        tc_norms_kernel<float><<<nchunk, 1024, 0, stream>>>(x4, nrm, cmn);
        tc_scan_kernel<float><<<nchunk, 1024, 0, stream>>>(nrm, cmn, out);
    }
}